// Round 11
// baseline (211.767 us; speedup 1.0000x reference)
//
#include <hip/hip_runtime.h>
#include <hip/hip_bf16.h>

// GAT on MI355X. Inputs fp32 (+ int32 adj); output fp32 [8 | 4096*8].
//  kA0: W fp32 -> Wt[32][4096] bf16 (B-operand layout for kA)
//  kI : WhB_t rows 8..15 init (row 8 = ones -> softmax denominator via MFMA)
//  kA : Wh = x @ W via MFMA bf16; epilogue -> WhB_t[h][o][n] bf16 + ssrc/sdst
//  kC : mhat[h] = max_n s_dst[h][n]
//  kD : MFMA attention: P-tile built in A-frag registers (exp/mask), one
//       mfma per 16x32 tile vs WhB_t; D col 8 = row-sum l; head-mean -> d_out+8
//  kE : per-row log_softmax + w_lin partial sums
//  kF : out[8] = sum partials + b_lin

typedef __attribute__((ext_vector_type(8))) short bf16x8;
typedef __attribute__((ext_vector_type(4))) float f32x4;
typedef __attribute__((ext_vector_type(4))) int   i32x4;

#define NN 4096
#define NC 8

__device__ __forceinline__ short f2bf(float f) {
  __hip_bfloat16 h = __float2bfloat16(f);
  return *reinterpret_cast<short*>(&h);
}

__device__ __forceinline__ bool is_adj(const void* p) {
  const unsigned* u = (const unsigned*)p;
  unsigned m = u[0] | u[1] | u[2] | u[3] | u[100] | u[1000];
  return m <= 1u;   // adj dwords are 0/1; fp32 N(0,1) bits never <= 1
}

// ---------- kA0: W[h][f][o] fp32 -> Wt[h*8+o][f] bf16 ----------
__global__ __launch_bounds__(256) void kA0(const float* __restrict__ W, short* __restrict__ Wt) {
  int idx = blockIdx.x * 256 + threadIdx.x;      // 131072
  int h = idx >> 15, r = idx & 32767, f = r >> 3, o = r & 7;
  Wt[(size_t)(h * 8 + o) * NN + f] = f2bf(W[idx]);
}

// ---------- kI: WhB_t[h][8..15][*]: row 8 = 1.0, rows 9..15 = 0 ----------
__global__ __launch_bounds__(256) void kI(short* __restrict__ WhBt) {
  int idx = blockIdx.x * 256 + threadIdx.x;      // 4*8*4096 = 131072
  int h = idx >> 15, r = idx & 32767, row = 8 + (r >> 12), f = r & 4095;
  WhBt[((size_t)h * 16 + row) * NN + f] = (row == 8) ? (short)0x3F80 : (short)0;
}

// ---------- kA: Wh = x @ W via MFMA, epilogue -> WhB_t bf16 + scores ----------
// 256 blocks x 512 thr (8 waves). Block: 16 rows x 32 cols; wave w: k-slice [w*512,(w+1)*512).
__global__ __launch_bounds__(512) void kA(const void* __restrict__ c0, const void* __restrict__ c1,
                                          const short* __restrict__ Wt,
                                          short* __restrict__ WhBt, float* __restrict__ ssrc,
                                          float* __restrict__ sdst, const float* __restrict__ a) {
  const float* x = (const float*)(is_adj(c0) ? c1 : c0);
  int m0 = blockIdx.x * 16;
  int t = threadIdx.x;
  int w = t >> 6, lane = t & 63;
  int mr = lane & 15, q = lane >> 4;
  const f32x4*  ap  = (const f32x4*)(x + (size_t)(m0 + mr) * NN + w * 512 + q * 8);
  const bf16x8* b0p = (const bf16x8*)(Wt + (size_t)mr        * NN + w * 512 + q * 8);
  const bf16x8* b1p = (const bf16x8*)(Wt + (size_t)(16 + mr) * NN + w * 512 + q * 8);
  f32x4 acc0 = {0.f, 0.f, 0.f, 0.f}, acc1 = {0.f, 0.f, 0.f, 0.f};
#pragma unroll 4
  for (int kk = 0; kk < 16; ++kk) {      // 16 k-steps of 32
    f32x4 xa = ap[kk * 8];
    f32x4 xb = ap[kk * 8 + 1];
    bf16x8 af;
#pragma unroll
    for (int e = 0; e < 4; ++e) { af[e] = f2bf(xa[e]); af[4 + e] = f2bf(xb[e]); }
    bf16x8 b0 = b0p[kk * 4];
    bf16x8 b1 = b1p[kk * 4];
    acc0 = __builtin_amdgcn_mfma_f32_16x16x32_bf16(af, b0, acc0, 0, 0, 0);
    acc1 = __builtin_amdgcn_mfma_f32_16x16x32_bf16(af, b1, acc1, 0, 0, 0);
  }
  __shared__ float red[8][16][32];
  __shared__ float whole[16][32];
#pragma unroll
  for (int r = 0; r < 4; ++r) {
    red[w][q * 4 + r][mr]      = acc0[r];
    red[w][q * 4 + r][16 + mr] = acc1[r];
  }
  __syncthreads();
  if (t < 512) {
    int m = t >> 5, c = t & 31;
    float s = 0.f;
#pragma unroll
    for (int ww = 0; ww < 8; ++ww) s += red[ww][m][c];
    whole[m][c] = s;
    int h = c >> 3, o = c & 7;
    WhBt[((size_t)h * 16 + o) * NN + m0 + m] = f2bf(s);
  }
  __syncthreads();
  if (t < 64) {
    int h = t >> 4, m = t & 15;
    float s1 = 0.f, s2 = 0.f;
#pragma unroll
    for (int o = 0; o < 8; ++o) {
      float v = whole[m][h * 8 + o];
      s1 += v * a[h * 16 + o];
      s2 += v * a[h * 16 + 8 + o];
    }
    ssrc[h * NN + m0 + m] = s1;
    sdst[h * NN + m0 + m] = s2;
  }
}

// ---------- kC: per-head global max of s_dst ----------
__global__ __launch_bounds__(256) void kC(const float* __restrict__ sdst, float* __restrict__ mhat) {
  int h = blockIdx.x, t = threadIdx.x;
  float m = -1e30f;
  for (int n = t; n < NN; n += 256) m = fmaxf(m, sdst[h * NN + n]);
  for (int mm = 1; mm <= 32; mm <<= 1) m = fmaxf(m, __shfl_xor(m, mm));
  __shared__ float sm[4];
  if ((t & 63) == 0) sm[t >> 6] = m;
  __syncthreads();
  if (t == 0) mhat[h] = fmaxf(fmaxf(sm[0], sm[1]), fmaxf(sm[2], sm[3]));
}

// ---------- kD: MFMA attention. 256 blocks x 512 thr (8 waves) ----------
// Wave w: head h = w&3, j-half = w>>2 (2048 j's, 64 chunks of 32).
// Lane (m=lane&15, q=lane>>4): A-frag P[m][k=q*8+e] computed in registers:
//   P = adj ? exp(lrelu(ssrc[m]+sdst[j]) - eb[m]) : 0,  eb = lrelu(ssrc+mhat) >= e
// B-frag from WhB_t[h][n=lane&15][j...]; rows 0-7 = Wh cols, row 8 = ones.
// D (col=lane&15, row=q*4+reg): cols 0-7 = PV partial, col 8 = denominator l.
__global__ __launch_bounds__(512) void kD(const void* __restrict__ c0, const void* __restrict__ c1,
                                          const short* __restrict__ WhBt,
                                          const float* __restrict__ ssrcg, const float* __restrict__ sdstg,
                                          const float* __restrict__ mhat,
                                          float* __restrict__ neF) {
  const int* adj = (const int*)(is_adj(c0) ? c0 : c1);
  int t = threadIdx.x;
  int w = t >> 6, lane = t & 63;
  int h = w & 3, half = w >> 2;
  int m = lane & 15, q = lane >> 4;
  int i0 = blockIdx.x * 16;
  int row = i0 + m;

  float ssr = ssrcg[h * NN + row];
  float mh = mhat[h];
  float tb = ssr + mh;
  float eb = fmaxf(tb, 0.2f * tb);
  const int*   arow = adj   + (size_t)row * NN;
  const float* sdr  = sdstg + (size_t)h * NN;
  const short* bp   = WhBt  + ((size_t)h * 16 + m) * NN;   // B row n = lane&15 (=m)

  f32x4 acc = {0.f, 0.f, 0.f, 0.f};
  int jbeg = half * 2048;
#pragma unroll 2
  for (int jc = jbeg; jc < jbeg + 2048; jc += 32) {
    int jb = jc + q * 8;
    i32x4 a0 = *(const i32x4*)(arow + jb);
    i32x4 a1 = *(const i32x4*)(arow + jb + 4);
    f32x4 s0 = *(const f32x4*)(sdr + jb);
    f32x4 s1 = *(const f32x4*)(sdr + jb + 4);
    bf16x8 af;
#pragma unroll
    for (int e = 0; e < 4; ++e) {
      float v0 = ssr + s0[e];
      float v1 = ssr + s1[e];
      float e0 = fmaxf(v0, 0.2f * v0);
      float e1 = fmaxf(v1, 0.2f * v1);
      float w0 = __expf(e0 - eb);
      float w1 = __expf(e1 - eb);
      w0 = (a0[e] > 0) ? w0 : 0.f;
      w1 = (a1[e] > 0) ? w1 : 0.f;
      af[e]     = f2bf(w0);
      af[4 + e] = f2bf(w1);
    }
    bf16x8 bfrg = *(const bf16x8*)(bp + jb);
    acc = __builtin_amdgcn_mfma_f32_16x16x32_bf16(af, bfrg, acc, 0, 0, 0);
  }
  __shared__ float sD[8][16][9];
  if (m <= 8) {
#pragma unroll
    for (int r = 0; r < 4; ++r) sD[w][q * 4 + r][m] = acc[r];
  }
  __syncthreads();
  if (t < 128) {
    int i = t >> 3, o = t & 7;
    float ne = 0.f;
#pragma unroll
    for (int hh = 0; hh < 4; ++hh) {
      float num = sD[hh][i][o] + sD[hh + 4][i][o];
      float den = sD[hh][i][8] + sD[hh + 4][i][8];
      ne += num / den;
    }
    neF[(size_t)(i0 + i) * NC + o] = 0.25f * ne;
  }
}

// ---------- kE: log_softmax rows + w_lin partial sums ----------
__global__ __launch_bounds__(128) void kE(const float* __restrict__ neF, const float* __restrict__ wlin,
                                          float* __restrict__ partials) {
  int t = threadIdx.x;
  int n = blockIdx.x * 128 + t;
  f32x4 v0 = *(const f32x4*)(neF + (size_t)n * NC);
  f32x4 v1 = *(const f32x4*)(neF + (size_t)n * NC + 4);
  float m = v0[0];
#pragma unroll
  for (int e = 1; e < 4; ++e) m = fmaxf(m, v0[e]);
#pragma unroll
  for (int e = 0; e < 4; ++e) m = fmaxf(m, v1[e]);
  float s = 0.f;
#pragma unroll
  for (int e = 0; e < 4; ++e) s += __expf(v0[e] - m);
#pragma unroll
  for (int e = 0; e < 4; ++e) s += __expf(v1[e] - m);
  float ln = m + __logf(s);
  float wl = wlin[n];
  float p[8];
#pragma unroll
  for (int e = 0; e < 4; ++e) p[e] = (v0[e] - ln) * wl;
#pragma unroll
  for (int e = 0; e < 4; ++e) p[4 + e] = (v1[e] - ln) * wl;
#pragma unroll
  for (int mm = 1; mm <= 32; mm <<= 1)
#pragma unroll
    for (int o = 0; o < 8; ++o) p[o] += __shfl_xor(p[o], mm);
  __shared__ float wsum[2][8];
  if ((t & 63) == 0)
#pragma unroll
    for (int o = 0; o < 8; ++o) wsum[t >> 6][o] = p[o];
  __syncthreads();
  if (t < 8) partials[blockIdx.x * 8 + t] = wsum[0][t] + wsum[1][t];
}

// ---------- kF: final out[8] ----------
__global__ __launch_bounds__(64) void kF(const float* __restrict__ partials, const float* __restrict__ blin,
                                         float* __restrict__ out) {
  int t = threadIdx.x;
  if (t < 8) {
    float s = blin[0];
    for (int b = 0; b < 32; ++b) s += partials[b * 8 + t];
    out[t] = s;
  }
}

extern "C" void kernel_launch(void* const* d_in, const int* in_sizes, int n_in,
                              void* d_out, int out_size, void* d_ws, size_t ws_size,
                              hipStream_t stream) {
  const void* big0 = nullptr; const void* big1 = nullptr;
  const float* W = nullptr; const float* a = nullptr;
  const float* wlin = nullptr; const float* blin = nullptr;
  for (int idx = 0; idx < n_in; ++idx) {
    int sz = in_sizes[idx];
    if (sz == NN * NN)          { if (!big0) big0 = d_in[idx]; else big1 = d_in[idx]; }
    else if (sz == 4 * NN * NC) W    = (const float*)d_in[idx];
    else if (sz == 64)          a    = (const float*)d_in[idx];
    else if (sz == NN)          wlin = (const float*)d_in[idx];
    else if (sz == 1)           blin = (const float*)d_in[idx];
  }
  float* outF = (float*)d_out;       // fp32: [8] out | [4096][8] node_embeddings
  float* neF  = outF + 8;

  char* ws = (char*)d_ws;                  // 919,808 B total
  short* Wt      = (short*)(ws + 0);       // 262144 B
  short* WhBt    = (short*)(ws + 262144);  // 524288 B  [4][16][4096] bf16
  float* ssrc    = (float*)(ws + 786432);  // 65536 B
  float* sdst    = (float*)(ws + 851968);  // 65536 B... (next)
  float* mhat    = (float*)(ws + 917504);  // 256 B
  float* partials= (float*)(ws + 917760);  // 1024 B

  kA0<<<512, 256, 0, stream>>>(W, Wt);
  kI <<<512, 256, 0, stream>>>(WhBt);
  kA <<<256, 512, 0, stream>>>(big0, big1, Wt, WhBt, ssrc, sdst, a);
  kC <<<4,   256, 0, stream>>>(sdst, mhat);
  kD <<<256, 512, 0, stream>>>(big0, big1, WhBt, ssrc, sdst, mhat, neF);
  kE <<<32,  128, 0, stream>>>(neF, wlin, partials);
  kF <<<1,   64,  0, stream>>>(partials, blin, outF);
}

// Round 12
// 208.253 us; speedup vs baseline: 1.0169x; 1.0169x over previous
//
#include <hip/hip_runtime.h>
#include <hip/hip_bf16.h>

// GAT on MI355X. Inputs fp32 (+ int32 adj); output fp32 [8 | 4096*8].
//  kA0: W fp32 -> Wt[32][4096] bf16
//  kI : WhB_t rows 8..15 init (row 8 = ones -> softmax denom via MFMA)
//  kA : Wh = x @ W via MFMA bf16, 1024 thr (16 waves = 16 K-slices);
//       epilogue -> WhB_t[h][o][n] bf16 + ssrc/sdst
//  kC : mhat[h] = max_n s_dst[h][n]
//  kD : MFMA attention, 1024 thr (16 waves = 4 heads x 4 j-quarters);
//       P-tile in A-frag registers; D col 8 = denominator; head-mean -> d_out+8
//  kE : per-row log_softmax + w_lin partial sums
//  kF : out[8] = sum partials + b_lin

typedef __attribute__((ext_vector_type(8))) short bf16x8;
typedef __attribute__((ext_vector_type(4))) float f32x4;
typedef __attribute__((ext_vector_type(4))) int   i32x4;

#define NN 4096
#define NC 8

__device__ __forceinline__ short f2bf(float f) {
  __hip_bfloat16 h = __float2bfloat16(f);
  return *reinterpret_cast<short*>(&h);
}

__device__ __forceinline__ bool is_adj(const void* p) {
  const unsigned* u = (const unsigned*)p;
  unsigned m = u[0] | u[1] | u[2] | u[3] | u[100] | u[1000];
  return m <= 1u;   // adj dwords are 0/1; fp32 N(0,1) bits never <= 1
}

// ---------- kA0: W[h][f][o] fp32 -> Wt[h*8+o][f] bf16 ----------
__global__ __launch_bounds__(256) void kA0(const float* __restrict__ W, short* __restrict__ Wt) {
  int idx = blockIdx.x * 256 + threadIdx.x;      // 131072
  int h = idx >> 15, r = idx & 32767, f = r >> 3, o = r & 7;
  Wt[(size_t)(h * 8 + o) * NN + f] = f2bf(W[idx]);
}

// ---------- kI: WhB_t[h][8..15][*]: row 8 = 1.0, rows 9..15 = 0 ----------
__global__ __launch_bounds__(256) void kI(short* __restrict__ WhBt) {
  int idx = blockIdx.x * 256 + threadIdx.x;      // 131072
  int h = idx >> 15, r = idx & 32767, row = 8 + (r >> 12), f = r & 4095;
  WhBt[((size_t)h * 16 + row) * NN + f] = (row == 8) ? (short)0x3F80 : (short)0;
}

// ---------- kA: Wh = x @ W via MFMA. 256 blocks x 1024 thr (16 waves/K-slices) ----------
__global__ __launch_bounds__(1024) void kA(const void* __restrict__ c0, const void* __restrict__ c1,
                                           const short* __restrict__ Wt,
                                           short* __restrict__ WhBt, float* __restrict__ ssrc,
                                           float* __restrict__ sdst, const float* __restrict__ a) {
  const float* x = (const float*)(is_adj(c0) ? c1 : c0);
  int m0 = blockIdx.x * 16;
  int t = threadIdx.x;
  int w = t >> 6, lane = t & 63;
  int mr = lane & 15, q = lane >> 4;
  const f32x4*  ap  = (const f32x4*)(x + (size_t)(m0 + mr) * NN + w * 256 + q * 8);
  const bf16x8* b0p = (const bf16x8*)(Wt + (size_t)mr        * NN + w * 256 + q * 8);
  const bf16x8* b1p = (const bf16x8*)(Wt + (size_t)(16 + mr) * NN + w * 256 + q * 8);
  f32x4 acc0 = {0.f, 0.f, 0.f, 0.f}, acc1 = {0.f, 0.f, 0.f, 0.f};
#pragma unroll
  for (int kk = 0; kk < 8; ++kk) {      // 8 k-steps of 32 (256-wide K-slice)
    f32x4 xa = ap[kk * 8];
    f32x4 xb = ap[kk * 8 + 1];
    bf16x8 af;
#pragma unroll
    for (int e = 0; e < 4; ++e) { af[e] = f2bf(xa[e]); af[4 + e] = f2bf(xb[e]); }
    bf16x8 b0 = b0p[kk * 4];
    bf16x8 b1 = b1p[kk * 4];
    acc0 = __builtin_amdgcn_mfma_f32_16x16x32_bf16(af, b0, acc0, 0, 0, 0);
    acc1 = __builtin_amdgcn_mfma_f32_16x16x32_bf16(af, b1, acc1, 0, 0, 0);
  }
  __shared__ float red[16][16][32];
  __shared__ float whole[16][32];
#pragma unroll
  for (int r = 0; r < 4; ++r) {
    red[w][q * 4 + r][mr]      = acc0[r];
    red[w][q * 4 + r][16 + mr] = acc1[r];
  }
  __syncthreads();
  if (t < 512) {
    int m = t >> 5, c = t & 31;
    float s = 0.f;
#pragma unroll
    for (int ww = 0; ww < 16; ++ww) s += red[ww][m][c];
    whole[m][c] = s;
    int h = c >> 3, o = c & 7;
    WhBt[((size_t)h * 16 + o) * NN + m0 + m] = f2bf(s);
  }
  __syncthreads();
  if (t < 64) {
    int h = t >> 4, m = t & 15;
    float s1 = 0.f, s2 = 0.f;
#pragma unroll
    for (int o = 0; o < 8; ++o) {
      float v = whole[m][h * 8 + o];
      s1 += v * a[h * 16 + o];
      s2 += v * a[h * 16 + 8 + o];
    }
    ssrc[h * NN + m0 + m] = s1;
    sdst[h * NN + m0 + m] = s2;
  }
}

// ---------- kC: per-head global max of s_dst ----------
__global__ __launch_bounds__(256) void kC(const float* __restrict__ sdst, float* __restrict__ mhat) {
  int h = blockIdx.x, t = threadIdx.x;
  float m = -1e30f;
  for (int n = t; n < NN; n += 256) m = fmaxf(m, sdst[h * NN + n]);
  for (int mm = 1; mm <= 32; mm <<= 1) m = fmaxf(m, __shfl_xor(m, mm));
  __shared__ float sm[4];
  if ((t & 63) == 0) sm[t >> 6] = m;
  __syncthreads();
  if (t == 0) mhat[h] = fmaxf(fmaxf(sm[0], sm[1]), fmaxf(sm[2], sm[3]));
}

// ---------- kD: MFMA attention. 256 blocks x 1024 thr (16 waves = 4 heads x 4 j-quarters) ----------
// Lane (m=lane&15, q=lane>>4): A-frag P[m][k=q*8+e] computed in registers:
//   P = adj ? exp(lrelu(ssrc[m]+sdst[j]) - eb[m]) : 0,  eb = lrelu(ssrc+mhat)
// B-frag from WhB_t[h][n=lane&15][j...]; rows 0-7 = Wh cols, row 8 = ones.
// D (col=lane&15, row=q*4+reg): cols 0-7 = PV partial, col 8 = denominator.
__global__ __launch_bounds__(1024) void kD(const void* __restrict__ c0, const void* __restrict__ c1,
                                           const short* __restrict__ WhBt,
                                           const float* __restrict__ ssrcg, const float* __restrict__ sdstg,
                                           const float* __restrict__ mhat,
                                           float* __restrict__ neF) {
  const int* adj = (const int*)(is_adj(c0) ? c0 : c1);
  int t = threadIdx.x;
  int w = t >> 6, lane = t & 63;
  int h = w & 3, qr = w >> 2;
  int m = lane & 15, q = lane >> 4;
  int i0 = blockIdx.x * 16;
  int row = i0 + m;

  float ssr = ssrcg[h * NN + row];
  float mh = mhat[h];
  float tb = ssr + mh;
  float eb = fmaxf(tb, 0.2f * tb);
  const int*   arow = adj   + (size_t)row * NN;
  const float* sdr  = sdstg + (size_t)h * NN;
  const short* bp   = WhBt  + ((size_t)h * 16 + m) * NN;

  f32x4 acc = {0.f, 0.f, 0.f, 0.f};
  int jbeg = qr * 1024;
#pragma unroll 4
  for (int jc = jbeg; jc < jbeg + 1024; jc += 32) {
    int jb = jc + q * 8;
    i32x4 a0 = *(const i32x4*)(arow + jb);
    i32x4 a1 = *(const i32x4*)(arow + jb + 4);
    f32x4 s0 = *(const f32x4*)(sdr + jb);
    f32x4 s1 = *(const f32x4*)(sdr + jb + 4);
    bf16x8 bfrg = *(const bf16x8*)(bp + jb);
    bf16x8 af;
#pragma unroll
    for (int e = 0; e < 4; ++e) {
      float v0 = ssr + s0[e];
      float v1 = ssr + s1[e];
      float e0 = fmaxf(v0, 0.2f * v0);
      float e1 = fmaxf(v1, 0.2f * v1);
      float w0 = __expf(e0 - eb);
      float w1 = __expf(e1 - eb);
      w0 = (a0[e] > 0) ? w0 : 0.f;
      w1 = (a1[e] > 0) ? w1 : 0.f;
      af[e]     = f2bf(w0);
      af[4 + e] = f2bf(w1);
    }
    acc = __builtin_amdgcn_mfma_f32_16x16x32_bf16(af, bfrg, acc, 0, 0, 0);
  }
  __shared__ float sD[16][16][9];
  if (m <= 8) {
#pragma unroll
    for (int r = 0; r < 4; ++r) sD[w][q * 4 + r][m] = acc[r];
  }
  __syncthreads();
  if (t < 128) {
    int i = t >> 3, o = t & 7;
    float ne = 0.f;
#pragma unroll
    for (int hh = 0; hh < 4; ++hh) {
      float num = 0.f, den = 0.f;
#pragma unroll
      for (int qq = 0; qq < 4; ++qq) {
        num += sD[qq * 4 + hh][i][o];
        den += sD[qq * 4 + hh][i][8];
      }
      ne += num / den;
    }
    neF[(size_t)(i0 + i) * NC + o] = 0.25f * ne;
  }
}

// ---------- kE: log_softmax rows + w_lin partial sums ----------
__global__ __launch_bounds__(128) void kE(const float* __restrict__ neF, const float* __restrict__ wlin,
                                          float* __restrict__ partials) {
  int t = threadIdx.x;
  int n = blockIdx.x * 128 + t;
  f32x4 v0 = *(const f32x4*)(neF + (size_t)n * NC);
  f32x4 v1 = *(const f32x4*)(neF + (size_t)n * NC + 4);
  float m = v0[0];
#pragma unroll
  for (int e = 1; e < 4; ++e) m = fmaxf(m, v0[e]);
#pragma unroll
  for (int e = 0; e < 4; ++e) m = fmaxf(m, v1[e]);
  float s = 0.f;
#pragma unroll
  for (int e = 0; e < 4; ++e) s += __expf(v0[e] - m);
#pragma unroll
  for (int e = 0; e < 4; ++e) s += __expf(v1[e] - m);
  float ln = m + __logf(s);
  float wl = wlin[n];
  float p[8];
#pragma unroll
  for (int e = 0; e < 4; ++e) p[e] = (v0[e] - ln) * wl;
#pragma unroll
  for (int e = 0; e < 4; ++e) p[4 + e] = (v1[e] - ln) * wl;
#pragma unroll
  for (int mm = 1; mm <= 32; mm <<= 1)
#pragma unroll
    for (int o = 0; o < 8; ++o) p[o] += __shfl_xor(p[o], mm);
  __shared__ float wsum[2][8];
  if ((t & 63) == 0)
#pragma unroll
    for (int o = 0; o < 8; ++o) wsum[t >> 6][o] = p[o];
  __syncthreads();
  if (t < 8) partials[blockIdx.x * 8 + t] = wsum[0][t] + wsum[1][t];
}

// ---------- kF: final out[8] ----------
__global__ __launch_bounds__(64) void kF(const float* __restrict__ partials, const float* __restrict__ blin,
                                         float* __restrict__ out) {
  int t = threadIdx.x;
  if (t < 8) {
    float s = blin[0];
    for (int b = 0; b < 32; ++b) s += partials[b * 8 + t];
    out[t] = s;
  }
}

extern "C" void kernel_launch(void* const* d_in, const int* in_sizes, int n_in,
                              void* d_out, int out_size, void* d_ws, size_t ws_size,
                              hipStream_t stream) {
  const void* big0 = nullptr; const void* big1 = nullptr;
  const float* W = nullptr; const float* a = nullptr;
  const float* wlin = nullptr; const float* blin = nullptr;
  for (int idx = 0; idx < n_in; ++idx) {
    int sz = in_sizes[idx];
    if (sz == NN * NN)          { if (!big0) big0 = d_in[idx]; else big1 = d_in[idx]; }
    else if (sz == 4 * NN * NC) W    = (const float*)d_in[idx];
    else if (sz == 64)          a    = (const float*)d_in[idx];
    else if (sz == NN)          wlin = (const float*)d_in[idx];
    else if (sz == 1)           blin = (const float*)d_in[idx];
  }
  float* outF = (float*)d_out;       // fp32: [8] out | [4096][8] node_embeddings
  float* neF  = outF + 8;

  char* ws = (char*)d_ws;                  // 919,808 B total
  short* Wt      = (short*)(ws + 0);       // 262144 B
  short* WhBt    = (short*)(ws + 262144);  // 524288 B  [4][16][4096] bf16
  float* ssrc    = (float*)(ws + 786432);  // 65536 B
  float* sdst    = (float*)(ws + 851968);  // 65536 B
  float* mhat    = (float*)(ws + 917504);  // 256 B
  float* partials= (float*)(ws + 917760);  // 1024 B

  kA0<<<512, 256,  0, stream>>>(W, Wt);
  kI <<<512, 256,  0, stream>>>(WhBt);
  kA <<<256, 1024, 0, stream>>>(big0, big1, Wt, WhBt, ssrc, sdst, a);
  kC <<<4,   256,  0, stream>>>(sdst, mhat);
  kD <<<256, 1024, 0, stream>>>(big0, big1, WhBt, ssrc, sdst, mhat, neF);
  kE <<<32,  128,  0, stream>>>(neF, wlin, partials);
  kF <<<1,   64,   0, stream>>>(partials, blin, outF);
}